// Round 9
// baseline (1844.856 us; speedup 1.0000x reference)
//
#include <hip/hip_runtime.h>
#include <cstdint>
#include <cstddef>

using f32x4 = float __attribute__((ext_vector_type(4)));
using u16x8 = unsigned short __attribute__((ext_vector_type(8)));
using u16x4 = unsigned short __attribute__((ext_vector_type(4)));
typedef _Float16 f16x8 __attribute__((ext_vector_type(8)));

#define DEV static __device__ __forceinline__

DEV unsigned short f2h(float f) {            // f32 -> fp16 bits (RNE via v_cvt_f16_f32)
  _Float16 x = (_Float16)f;
  return __builtin_bit_cast(unsigned short, x);
}
DEV float h2f(unsigned short s) {
  return (float)__builtin_bit_cast(_Float16, s);
}
DEV float sigm(float x) { return 1.f / (1.f + __expf(-x)); }
DEV float tanh_(float x) { return 2.f / (1.f + __expf(-2.f * x)) - 1.f; }

#define MFMA_F16(acc, va, vb) \
  acc = __builtin_amdgcn_mfma_f32_16x16x32_f16(va, vb, acc, 0, 0, 0)

constexpr int NB = 1024;   // minibatch
constexpr int AT = 128;    // atoms
constexpr int DD = 256;    // hidden dim
constexpr int MOUT = 512;  // readout M
constexpr long NR = (long)NB * AT;   // 131072 rows

// counted-vmcnt wait + scheduling fences (rule #18: fence after asm wait)
#define VWAIT(n) do { asm volatile("s_waitcnt vmcnt(" #n ")" ::: "memory"); \
                      __builtin_amdgcn_sched_barrier(0); } while (0)
#define LWAIT do { asm volatile("s_waitcnt lgkmcnt(0)" ::: "memory"); \
                   __builtin_amdgcn_sched_barrier(0); } while (0)
#define BARR do { __builtin_amdgcn_sched_barrier(0); __builtin_amdgcn_s_barrier(); \
                  __builtin_amdgcn_sched_barrier(0); } while (0)

// XCD-chunked bijective swizzle (T1, proven round 5: FETCH 277->69 MB):
// blocks sharing operand panels become contiguous within one XCD's chunk.
// Requires n % 8 == 0 (all our grids are).
#define XCD_SWZ(WG, N) const int WG = ((int)blockIdx.x & 7) * ((N) / 8) + ((int)blockIdx.x >> 3);

// ---------------- generic f32 -> fp16 convert (8 elems/thread; n % 2048 == 0) ----------------
__global__ __launch_bounds__(256) void k_cvt(const float* __restrict__ src,
                                             unsigned short* __restrict__ dst) {
  long base = ((long)blockIdx.x * 256 + threadIdx.x) * 8;
  f32x4 v0 = *(const f32x4*)(src + base);
  f32x4 v1 = *(const f32x4*)(src + base + 4);
  u16x8 o;
  #pragma unroll
  for (int q = 0; q < 4; ++q) o[q] = f2h(v0[q]);
  #pragma unroll
  for (int q = 0; q < 4; ++q) o[4 + q] = f2h(v1[q]);
  *(u16x8*)(dst + base) = o;
}

// ---------------- merged weight converts: 5 tensors, one dispatch (768 blocks) ----------------
// blocks: [0,384) msg_W | [384,480) W_ih | [480,576) W_hh | [576,704) i_W | [704,768) j_W
__global__ __launch_bounds__(256) void k_cvt5(const float* __restrict__ s0, unsigned short* __restrict__ d0,
                                              const float* __restrict__ s1, unsigned short* __restrict__ d1,
                                              const float* __restrict__ s2, unsigned short* __restrict__ d2,
                                              const float* __restrict__ s3, unsigned short* __restrict__ d3,
                                              const float* __restrict__ s4, unsigned short* __restrict__ d4) {
  int blk = blockIdx.x;
  const float* s; unsigned short* d;
  if (blk < 384)      { s = s0; d = d0; }
  else if (blk < 480) { s = s1; d = d1; blk -= 384; }
  else if (blk < 576) { s = s2; d = d2; blk -= 480; }
  else if (blk < 704) { s = s3; d = d3; blk -= 576; }
  else                { s = s4; d = d4; blk -= 704; }
  long base = ((long)blk * 256 + threadIdx.x) * 8;
  f32x4 v0 = *(const f32x4*)(s + base);
  f32x4 v1 = *(const f32x4*)(s + base + 4);
  u16x8 o;
  #pragma unroll
  for (int q = 0; q < 4; ++q) o[q] = f2h(v0[q]);
  #pragma unroll
  for (int q = 0; q < 4; ++q) o[4 + q] = f2h(v1[q]);
  *(u16x8*)(d + base) = o;
}

// ---------------- embed gather: h and h0 (fp16) ----------------
__global__ __launch_bounds__(256) void k_gather(const int* __restrict__ atom,
                                                const float* __restrict__ embed,
                                                unsigned short* __restrict__ h,
                                                unsigned short* __restrict__ h0) {
  long idx = (long)blockIdx.x * 256 + threadIdx.x;   // NR*64 threads, 4 elems each
  long n = idx >> 6;
  int ch = (int)(idx & 63);
  int a = atom[n];
  f32x4 v = *(const f32x4*)(embed + (size_t)a * DD + ch * 4);
  u16x4 o;
  #pragma unroll
  for (int q = 0; q < 4; ++q) o[q] = f2h(v[q]);
  *(u16x4*)(h  + n * DD + ch * 4) = o;
  *(u16x4*)(h0 + n * DD + ch * 4) = o;
}

// ---- shared helpers ----
// LDS XOR-swizzle (proven round 3: conflicts 1.7e7 -> 0):
// store data-seg s of row r at physical seg p = s ^ ((r>>1)&3).
//   write side (DMA is linear): pre-swizzle GLOBAL source chunk per lane.
//   read side: physical seg = lg ^ ((l15>>1)&3).
#define GEMM_IDS \
  const int tid = threadIdx.x, lane = tid & 63, wave = tid >> 6; \
  const int wr = wave >> 1, wc = wave & 1; \
  const int l15 = lane & 15, lg = lane >> 4; \
  const int sseg = (l15 >> 1) & 3;

// async global -> LDS stage of a 128x32 fp16 tile (2 vmem ops/wave, 4-wave blocks)
#define GLDS(SRC, STRIDE, DST) \
  { \
    _Pragma("unroll") \
    for (int j_ = 0; j_ < 2; ++j_) { \
      const unsigned short* g_ = (SRC) + \
          (size_t)((wave * 2 + j_) * 16 + (lane >> 2)) * (STRIDE) + \
          ((lane & 3) ^ ((lane >> 3) & 3)) * 8; \
      __builtin_amdgcn_global_load_lds( \
          (const __attribute__((address_space(1))) void*)g_, \
          (__attribute__((address_space(3))) void*)&DST[(wave * 2 + j_) * 16][0], \
          16, 0, 0); \
    } \
  }

#define LOAD_A(AH) \
  f16x8 ah[4]; \
  _Pragma("unroll") \
  for (int m_ = 0; m_ < 4; ++m_) \
    ah[m_] = *(const f16x8*)&AH[wr * 64 + m_ * 16 + l15][(lg ^ sseg) * 8];

#define LOAD_B(BH) \
  f16x8 bh[4]; \
  _Pragma("unroll") \
  for (int n_ = 0; n_ < 4; ++n_) \
    bh[n_] = *(const f16x8*)&BH[wc * 64 + n_ * 16 + l15][(lg ^ sseg) * 8];

#define MFMA_TILE(ACC) \
  _Pragma("unroll") \
  for (int m_ = 0; m_ < 4; ++m_) \
    _Pragma("unroll") \
    for (int n_ = 0; n_ < 4; ++n_) \
      MFMA_F16(ACC[m_][n_], ah[m_], bh[n_]);

// ---------------- fused msg GEMM + adjacency bmm, fully double-buffered (round-4 proven) ----------------
// grid 2048 (1D, XCD-swizzled): wg>>1 = batch, wg&1 = d-half (both halves share h reads -> same XCD)
__global__ __launch_bounds__(256) void k_msgadj(const unsigned short* __restrict__ h,    // [NR][256]
                                                const unsigned short* __restrict__ W,    // msg_W[step] fp16 [1024][256]
                                                const float* __restrict__ bias,          // msg_b[step] [1024]
                                                const unsigned short* __restrict__ adjh, // fp16 [b][e][128][128]
                                                unsigned short* __restrict__ m_out) {    // [NR][256]
  __shared__ __align__(16) char pool[16384 + 128 * 136 * 2];   // 16KB buf0 + 34.8KB (buf1|PT)
  typedef unsigned short row32[32];
  row32* As_[2] = { (row32*)pool,          (row32*)(pool + 16384) };
  row32* Bs_[2] = { (row32*)(pool + 8192), (row32*)(pool + 24576) };
  unsigned short (*PT)[136] = (unsigned short (*)[136])(pool + 16384);
  GEMM_IDS
  XCD_SWZ(wg, 2048)
  const size_t b = wg >> 1;
  const int d0 = (wg & 1) * 128;
  const unsigned short* hb = h + (size_t)b * 128 * 256;
  const unsigned short* adjb = adjh + (size_t)b * 4 * 128 * 128;
  f32x4 accM[4][4] = {};
  for (int e = 0; e < 4; ++e) {
    f32x4 accP[4][4] = {};
    const unsigned short* We = W + (size_t)(e * 256 + d0) * 256;
    const unsigned short* adje = adjb + (size_t)e * 128 * 128;
    // ---- GEMM-1: 8 K-phases, 2-buffer depth-1 pipeline ----
    GLDS(hb, 256, As_[0])
    GLDS(We, 256, Bs_[0])
    #pragma unroll
    for (int k0i = 0; k0i < 8; ++k0i) {
      const int cur = k0i & 1;
      if (k0i < 7) {
        row32* an_ = As_[cur ^ 1];
        row32* bn_ = Bs_[cur ^ 1];
        GLDS(hb + (k0i + 1) * 32, 256, an_)
        GLDS(We + (k0i + 1) * 32, 256, bn_)
      } else {
        // last phase reads buf1; As0/Bs0 are free -> pre-stage adj(0), adj(1)
        GLDS(adje + 0 * 32, 128, As_[0])
        GLDS(adje + 1 * 32, 128, Bs_[0])
      }
      VWAIT(4);   // drain stage(k0i), keep the 4 just-issued
      BARR;
      {
        row32* ac_ = As_[cur];
        row32* bc_ = Bs_[cur];
        LOAD_A(ac_)
        LOAD_B(bc_)
        MFMA_TILE(accP)
      }
      BARR;
    }
    // ---- PT epilogue (writes alias buf1; GEMM-1 phase-7 reads are barrier-complete) ----
    #pragma unroll
    for (int m_ = 0; m_ < 4; ++m_) {
      int j0 = wr * 64 + m_ * 16 + lg * 4;
      #pragma unroll
      for (int n_ = 0; n_ < 4; ++n_) {
        int c = wc * 64 + n_ * 16 + l15;          // d-local
        float bb = bias[e * 256 + d0 + c];
        u16x4 o;
        #pragma unroll
        for (int q = 0; q < 4; ++q) o[q] = f2h(accP[m_][n_][q] + bb);
        *(u16x4*)&PT[c][j0] = o;
      }
    }
    LWAIT;   // commit ds_writes (raw barrier does not drain lgkm)
    BARR;
    // ---- adj-bmm: 4 phases, adj tiles ping-pong As0/Bs0, depth-1 ----
    #pragma unroll
    for (int kt = 0; kt < 4; ++kt) {
      if (kt == 1) { GLDS(adje + 2 * 32, 128, As_[0]) }   // adj(2) over adj(0)'s slot
      if (kt == 2) { GLDS(adje + 3 * 32, 128, Bs_[0]) }   // adj(3) over adj(1)'s slot
      if (kt < 3) { VWAIT(2); } else { VWAIT(0); }
      BARR;
      {
        row32* ac_ = (kt & 1) ? Bs_[0] : As_[0];
        LOAD_A(ac_)
        f16x8 bh[4];
        #pragma unroll
        for (int n_ = 0; n_ < 4; ++n_)
          bh[n_] = *(const f16x8*)&PT[wc * 64 + n_ * 16 + l15][kt * 32 + lg * 8];
        MFMA_TILE(accM)
      }
      BARR;
    }
  }
  #pragma unroll
  for (int m_ = 0; m_ < 4; ++m_) {
    int i0 = wr * 64 + m_ * 16 + lg * 4;
    #pragma unroll
    for (int n_ = 0; n_ < 4; ++n_) {
      int c = d0 + wc * 64 + n_ * 16 + l15;
      #pragma unroll
      for (int q = 0; q < 4; ++q)
        m_out[((size_t)b * 128 + i0 + q) * 256 + c] = f2h(accM[m_][n_][q]);
    }
  }
}

// ---------------- fused gates + GRU: NO-LDS direct-global fragment streaming ----------------
// grid 8192 (1D, XCD-swizzled): wg>>3 = batch, quad = wg&7; r0=(quad>>2)*64, c0=(quad&3)*64.
// Rationale (r8 post-mortem): the LDS-staged barrier-synced structure floors at ~200us
// regardless of tile shape/depth/occupancy (MFMA floor 50us, LDS floor 51-82us, HBM 21us).
// Post-T1 all operands are L2-resident; the 16x16x32 fragment layout is 4 lanes x 16B = 64B
// contiguous per row -> load fragments DIRECTLY from global (aligned 16B/lane), zero LDS,
// zero barriers, zero waitcnt drains. Each wave = independent streaming GEMM; the compiler
// schedules vmcnt for the register double-buffer (no inter-wave sync to defeat it).
// Per wave: 32x32 output, 16 k-tiles x {8 x 16B loads -> 12 MFMA}. L2 traffic ~1GB ≈ 30us.
template <bool HAS_H>
__global__ __launch_bounds__(256) void k_grufuse(const unsigned short* __restrict__ m,
                                                 const unsigned short* __restrict__ h,
                                                 const unsigned short* __restrict__ wih,  // [768][256]
                                                 const unsigned short* __restrict__ whh,  // [768][256]
                                                 const float* __restrict__ b_ih,
                                                 const float* __restrict__ b_hh,
                                                 unsigned short* __restrict__ h_new) {
  const int tid = threadIdx.x, lane = tid & 63, wave = tid >> 6;
  const int wr = wave >> 1, wc = wave & 1;
  const int l15 = lane & 15, lg = lane >> 4;
  XCD_SWZ(wg, 8192)
  const size_t b = wg >> 3;
  const int quad = wg & 7;
  const int r0 = (quad >> 2) * 64;
  const int c0 = (quad & 3) * 64;

  // per-lane fragment base pointers (A: row l15, k-chunk lg*8 ; B: weight-row l15, same)
  const unsigned short* msrc = m + ((size_t)b * 128 + r0 + wr * 32 + l15) * 256 + lg * 8;
  const unsigned short* hsrc = h + ((size_t)b * 128 + r0 + wr * 32 + l15) * 256 + lg * 8;
  const size_t bofs = (size_t)(c0 + wc * 32 + l15) * 256 + lg * 8;
  const unsigned short* wi = wih + bofs;
  const unsigned short* wh = whh + bofs;

  constexpr int NKT = HAS_H ? 16 : 8;
  f32x4 accR[2][2] = {}, accZ[2][2] = {}, accI[2][2] = {}, accN[2][2] = {};

  f16x8 a_[2][2], br_[2][2], bz_[2][2], bn_[2][2];   // [buf][frag] — all indices compile-time

  auto load_tile = [&](int t, int s) {
    const unsigned short* A = (HAS_H && t >= 8) ? hsrc : msrc;
    const unsigned short* W = (HAS_H && t >= 8) ? wh : wi;
    const int ko = (t & 7) * 32;
    #pragma unroll
    for (int m_ = 0; m_ < 2; ++m_)
      a_[s][m_] = *(const f16x8*)(A + (size_t)(m_ * 16) * 256 + ko);
    #pragma unroll
    for (int n_ = 0; n_ < 2; ++n_) {
      br_[s][n_] = *(const f16x8*)(W + (size_t)(0 * 256 + n_ * 16) * 256 + ko);
      bz_[s][n_] = *(const f16x8*)(W + (size_t)(1 * 256 + n_ * 16) * 256 + ko);
      bn_[s][n_] = *(const f16x8*)(W + (size_t)(2 * 256 + n_ * 16) * 256 + ko);
    }
  };

  load_tile(0, 0);
  #pragma unroll
  for (int kt = 0; kt < NKT; ++kt) {
    const int cur = kt & 1;                    // compile-time after full unroll
    if (kt + 1 < NKT) load_tile(kt + 1, cur ^ 1);
    #pragma unroll
    for (int m_ = 0; m_ < 2; ++m_)
      #pragma unroll
      for (int n_ = 0; n_ < 2; ++n_) {
        MFMA_F16(accR[m_][n_], a_[cur][m_], br_[cur][n_]);
        MFMA_F16(accZ[m_][n_], a_[cur][m_], bz_[cur][n_]);
        if (!HAS_H || kt < 8) { MFMA_F16(accI[m_][n_], a_[cur][m_], bn_[cur][n_]); }
        else                  { MFMA_F16(accN[m_][n_], a_[cur][m_], bn_[cur][n_]); }
      }
  }

  // epilogue: full-f32 GRU combine (wave owns 32 rows x 32 cols at (r0+wr*32, c0+wc*32))
  #pragma unroll
  for (int m_ = 0; m_ < 2; ++m_) {
    int rloc = r0 + wr * 32 + m_ * 16 + lg * 4;
    #pragma unroll
    for (int n_ = 0; n_ < 2; ++n_) {
      int c = c0 + wc * 32 + n_ * 16 + l15;
      float br = b_ih[c] + b_hh[c];
      float bz = b_ih[256 + c] + b_hh[256 + c];
      float bin = b_ih[512 + c], bhn = b_hh[512 + c];
      #pragma unroll
      for (int q = 0; q < 4; ++q) {
        size_t row = (size_t)b * 128 + rloc + q;
        float r = sigm(accR[m_][n_][q] + br);
        float z = sigm(accZ[m_][n_][q] + bz);
        float hn = (HAS_H ? accN[m_][n_][q] : 0.f) + bhn;
        float nn = tanh_(accI[m_][n_][q] + bin + r * hn);
        float hv = HAS_H ? h2f(h[row * 256 + c]) : 0.f;
        h_new[row * 256 + c] = f2h((1.f - z) * nn + z * hv);
      }
    }
  }
}

// ---------------- fused readout (2-deep counted-vmcnt pipeline) ----------------
// grid 4096 (1D, XCD-swizzled): wg>>2 = batch, wg&3 = col-tile (4 sharers of h/h0)
__global__ __launch_bounds__(256) void k_readout(const unsigned short* __restrict__ h,
                                                 const unsigned short* __restrict__ h0,
                                                 const unsigned short* __restrict__ iw,   // [512][512]
                                                 const unsigned short* __restrict__ jw,   // [512][256]
                                                 const float* __restrict__ ib,
                                                 const float* __restrict__ jb,
                                                 float* __restrict__ out) {
  __shared__ unsigned short As[2][128][32];
  __shared__ unsigned short Bg[2][128][32], Bv[2][128][32];
  __shared__ float red[2][128];
  GEMM_IDS
  XCD_SWZ(wg, 4096)
  const size_t b = wg >> 2;
  const int c0 = (wg & 3) * 128;
  auto as_src = [&](int t) {
    return (t < 8) ? (h + b * 128 * 256 + t * 32) : (h0 + b * 128 * 256 + (t - 8) * 32);
  };
  f32x4 accG[4][4] = {};
  f32x4 accV[4][4] = {};
  GLDS(as_src(0), 256, As[0])
  GLDS(iw + (size_t)c0 * 512, 512, Bg[0])
  GLDS(jw + (size_t)c0 * 256, 256, Bv[0])
  #pragma unroll
  for (int kt = 0; kt < 16; ++kt) {
    const int cur = kt & 1;
    if (kt + 1 < 16) {
      GLDS(as_src(kt + 1), 256, As[cur ^ 1])
      GLDS(iw + (size_t)c0 * 512 + (kt + 1) * 32, 512, Bg[cur ^ 1])
      if (kt + 1 < 8) GLDS(jw + (size_t)c0 * 256 + (kt + 1) * 32, 256, Bv[cur ^ 1])
    }
    if (kt < 7) { VWAIT(6); } else if (kt < 15) { VWAIT(4); } else { VWAIT(0); }
    BARR;
    LOAD_A(As[cur])
    f16x8 bg[4];
    #pragma unroll
    for (int n_ = 0; n_ < 4; ++n_)
      bg[n_] = *(const f16x8*)&Bg[cur][wc * 64 + n_ * 16 + l15][(lg ^ sseg) * 8];
    #pragma unroll
    for (int m_ = 0; m_ < 4; ++m_)
      #pragma unroll
      for (int n_ = 0; n_ < 4; ++n_)
        MFMA_F16(accG[m_][n_], ah[m_], bg[n_]);
    if (kt < 8) {
      f16x8 bv[4];
      #pragma unroll
      for (int n_ = 0; n_ < 4; ++n_)
        bv[n_] = *(const f16x8*)&Bv[cur][wc * 64 + n_ * 16 + l15][(lg ^ sseg) * 8];
      #pragma unroll
      for (int m_ = 0; m_ < 4; ++m_)
        #pragma unroll
        for (int n_ = 0; n_ < 4; ++n_)
          MFMA_F16(accV[m_][n_], ah[m_], bv[n_]);
    }
    BARR;
  }
  #pragma unroll
  for (int n_ = 0; n_ < 4; ++n_) {
    int c = c0 + wc * 64 + n_ * 16 + l15;
    float gb = ib[c], vb = jb[c];
    float s = 0.f;
    #pragma unroll
    for (int m_ = 0; m_ < 4; ++m_)
      #pragma unroll
      for (int q = 0; q < 4; ++q) {
        float g = sigm(accG[m_][n_][q] + gb);
        float v = accV[m_][n_][q] + vb;
        s += g * v;
      }
    s += __shfl_xor(s, 16);
    s += __shfl_xor(s, 32);
    if (lg == 0) red[wr][wc * 64 + n_ * 16 + l15] = s;
  }
  __syncthreads();
  if (tid < 128) out[b * MOUT + c0 + tid] = red[0][tid] + red[1][tid];
}

// ---------------- host ----------------
extern "C" void kernel_launch(void* const* d_in, const int* in_sizes, int n_in,
                              void* d_out, int out_size, void* d_ws, size_t ws_size,
                              hipStream_t stream) {
  const int*   atom  = (const int*)d_in[0];
  const float* adj   = (const float*)d_in[1];
  const float* embed = (const float*)d_in[2];
  const float* msg_W = (const float*)d_in[3];
  const float* msg_b = (const float*)d_in[4];
  const float* W_ih  = (const float*)d_in[5];
  const float* b_ih  = (const float*)d_in[6];
  const float* W_hh  = (const float*)d_in[7];
  const float* b_hh  = (const float*)d_in[8];
  const float* i_W   = (const float*)d_in[9];
  const float* i_b   = (const float*)d_in[10];
  const float* j_W   = (const float*)d_in[11];
  const float* j_b   = (const float*)d_in[12];
  float* out = (float*)d_out;

  const size_t SZ_H   = (size_t)NR * 256 * 2;              // 67 MB
  const size_t SZ_ADJ = (size_t)NB * 4 * 128 * 128 * 2;    // 134 MB

  char* p = (char*)d_ws;
  unsigned short* hA   = (unsigned short*)p;  p += SZ_H;
  unsigned short* hB   = (unsigned short*)p;  p += SZ_H;
  unsigned short* h0   = (unsigned short*)p;  p += SZ_H;
  unsigned short* m    = (unsigned short*)p;  p += SZ_H;
  unsigned short* adjh = (unsigned short*)p;  p += SZ_ADJ;
  unsigned short* wmsg = (unsigned short*)p;  p += (size_t)3 * 1024 * 256 * 2;
  unsigned short* wih  = (unsigned short*)p;  p += (size_t)768 * 256 * 2;
  unsigned short* whh  = (unsigned short*)p;  p += (size_t)768 * 256 * 2;
  unsigned short* wiw  = (unsigned short*)p;  p += (size_t)512 * 512 * 2;
  unsigned short* wjw  = (unsigned short*)p;  p += (size_t)512 * 256 * 2;
  if ((size_t)(p - (char*)d_ws) > ws_size) return;  // insufficient workspace -> visible failure

  // converts: adj (BW-bound) + all 5 weights in one dispatch
  k_cvt<<<(int)((size_t)NB * 4 * 128 * 128 / 2048), 256, 0, stream>>>(adj, adjh);
  k_cvt5<<<768, 256, 0, stream>>>(msg_W, wmsg, W_ih, wih, W_hh, whh, i_W, wiw, j_W, wjw);

  // gather
  k_gather<<<(int)(NR * 64 / 256), 256, 0, stream>>>(atom, embed, hA, h0);

  unsigned short* h_cur = hA;
  unsigned short* h_nxt = hB;
  for (int step = 0; step < 3; ++step) {
    // fused: m = einsum(adj, reshape(h @ msg_W^T + msg_b))
    k_msgadj<<<2048, 256, 0, stream>>>(h_cur, wmsg + (size_t)step * 262144,
                                       msg_b + (size_t)step * 1024, adjh, m);
    if (step == 0)
      k_grufuse<false><<<8192, 256, 0, stream>>>(m, h_cur, wih, whh, b_ih, b_hh, h_nxt);
    else
      k_grufuse<true><<<8192, 256, 0, stream>>>(m, h_cur, wih, whh, b_ih, b_hh, h_nxt);
    unsigned short* t = h_cur; h_cur = h_nxt; h_nxt = t;
  }

  // fused gated readout
  k_readout<<<4096, 256, 0, stream>>>(h_cur, h0, wiw, wjw, i_b, j_b, out);
}

// Round 10
// 1133.212 us; speedup vs baseline: 1.6280x; 1.6280x over previous
//
#include <hip/hip_runtime.h>
#include <cstdint>
#include <cstddef>

using f32x4 = float __attribute__((ext_vector_type(4)));
using u16x8 = unsigned short __attribute__((ext_vector_type(8)));
using u16x4 = unsigned short __attribute__((ext_vector_type(4)));
typedef _Float16 f16x8 __attribute__((ext_vector_type(8)));

#define DEV static __device__ __forceinline__

DEV unsigned short f2h(float f) {            // f32 -> fp16 bits (RNE via v_cvt_f16_f32)
  _Float16 x = (_Float16)f;
  return __builtin_bit_cast(unsigned short, x);
}
DEV float h2f(unsigned short s) {
  return (float)__builtin_bit_cast(_Float16, s);
}
DEV float sigm(float x) { return 1.f / (1.f + __expf(-x)); }
DEV float tanh_(float x) { return 2.f / (1.f + __expf(-2.f * x)) - 1.f; }

#define MFMA_F16(acc, va, vb) \
  acc = __builtin_amdgcn_mfma_f32_16x16x32_f16(va, vb, acc, 0, 0, 0)

constexpr int NB = 1024;   // minibatch
constexpr int AT = 128;    // atoms
constexpr int DD = 256;    // hidden dim
constexpr int MOUT = 512;  // readout M
constexpr long NR = (long)NB * AT;   // 131072 rows

// counted-vmcnt wait + scheduling fences (rule #18: fence after asm wait)
#define VWAIT(n) do { asm volatile("s_waitcnt vmcnt(" #n ")" ::: "memory"); \
                      __builtin_amdgcn_sched_barrier(0); } while (0)
#define LWAIT do { asm volatile("s_waitcnt lgkmcnt(0)" ::: "memory"); \
                   __builtin_amdgcn_sched_barrier(0); } while (0)
#define BARR do { __builtin_amdgcn_sched_barrier(0); __builtin_amdgcn_s_barrier(); \
                  __builtin_amdgcn_sched_barrier(0); } while (0)

// XCD-chunked bijective swizzle (T1, proven round 5: FETCH 277->69 MB):
// blocks sharing operand panels become contiguous within one XCD's chunk.
// Requires n % 8 == 0 (all our grids are).
#define XCD_SWZ(WG, N) const int WG = ((int)blockIdx.x & 7) * ((N) / 8) + ((int)blockIdx.x >> 3);

// ---------------- generic f32 -> fp16 convert (8 elems/thread; n % 2048 == 0) ----------------
__global__ __launch_bounds__(256) void k_cvt(const float* __restrict__ src,
                                             unsigned short* __restrict__ dst) {
  long base = ((long)blockIdx.x * 256 + threadIdx.x) * 8;
  f32x4 v0 = *(const f32x4*)(src + base);
  f32x4 v1 = *(const f32x4*)(src + base + 4);
  u16x8 o;
  #pragma unroll
  for (int q = 0; q < 4; ++q) o[q] = f2h(v0[q]);
  #pragma unroll
  for (int q = 0; q < 4; ++q) o[4 + q] = f2h(v1[q]);
  *(u16x8*)(dst + base) = o;
}

// ---------------- merged weight converts: 5 tensors, one dispatch (768 blocks) ----------------
// blocks: [0,384) msg_W | [384,480) W_ih | [480,576) W_hh | [576,704) i_W | [704,768) j_W
__global__ __launch_bounds__(256) void k_cvt5(const float* __restrict__ s0, unsigned short* __restrict__ d0,
                                              const float* __restrict__ s1, unsigned short* __restrict__ d1,
                                              const float* __restrict__ s2, unsigned short* __restrict__ d2,
                                              const float* __restrict__ s3, unsigned short* __restrict__ d3,
                                              const float* __restrict__ s4, unsigned short* __restrict__ d4) {
  int blk = blockIdx.x;
  const float* s; unsigned short* d;
  if (blk < 384)      { s = s0; d = d0; }
  else if (blk < 480) { s = s1; d = d1; blk -= 384; }
  else if (blk < 576) { s = s2; d = d2; blk -= 480; }
  else if (blk < 704) { s = s3; d = d3; blk -= 576; }
  else                { s = s4; d = d4; blk -= 704; }
  long base = ((long)blk * 256 + threadIdx.x) * 8;
  f32x4 v0 = *(const f32x4*)(s + base);
  f32x4 v1 = *(const f32x4*)(s + base + 4);
  u16x8 o;
  #pragma unroll
  for (int q = 0; q < 4; ++q) o[q] = f2h(v0[q]);
  #pragma unroll
  for (int q = 0; q < 4; ++q) o[4 + q] = f2h(v1[q]);
  *(u16x8*)(d + base) = o;
}

// ---------------- embed gather: h and h0 (fp16) ----------------
__global__ __launch_bounds__(256) void k_gather(const int* __restrict__ atom,
                                                const float* __restrict__ embed,
                                                unsigned short* __restrict__ h,
                                                unsigned short* __restrict__ h0) {
  long idx = (long)blockIdx.x * 256 + threadIdx.x;   // NR*64 threads, 4 elems each
  long n = idx >> 6;
  int ch = (int)(idx & 63);
  int a = atom[n];
  f32x4 v = *(const f32x4*)(embed + (size_t)a * DD + ch * 4);
  u16x4 o;
  #pragma unroll
  for (int q = 0; q < 4; ++q) o[q] = f2h(v[q]);
  *(u16x4*)(h  + n * DD + ch * 4) = o;
  *(u16x4*)(h0 + n * DD + ch * 4) = o;
}

// ---- shared helpers ----
// LDS XOR-swizzle (proven round 3: conflicts 1.7e7 -> 0):
// store data-seg s of row r at physical seg p = s ^ ((r>>1)&3).
//   write side (DMA is linear): pre-swizzle GLOBAL source chunk per lane.
//   read side: physical seg = lg ^ ((l15>>1)&3).
#define GEMM_IDS \
  const int tid = threadIdx.x, lane = tid & 63, wave = tid >> 6; \
  const int wr = wave >> 1, wc = wave & 1; \
  const int l15 = lane & 15, lg = lane >> 4; \
  const int sseg = (l15 >> 1) & 3;

// async global -> LDS stage of a 128x32 fp16 tile (2 vmem ops/wave), source pre-swizzled
#define GLDS(SRC, STRIDE, DST) \
  { \
    _Pragma("unroll") \
    for (int j_ = 0; j_ < 2; ++j_) { \
      const unsigned short* g_ = (SRC) + \
          (size_t)((wave * 2 + j_) * 16 + (lane >> 2)) * (STRIDE) + \
          ((lane & 3) ^ ((lane >> 3) & 3)) * 8; \
      __builtin_amdgcn_global_load_lds( \
          (const __attribute__((address_space(1))) void*)g_, \
          (__attribute__((address_space(3))) void*)&DST[(wave * 2 + j_) * 16][0], \
          16, 0, 0); \
    } \
  }

// async global -> LDS stage of a 64x32 fp16 tile (1 vmem op/wave), source pre-swizzled
#define GLDS64(SRC, STRIDE, DST) \
  { \
    const unsigned short* g_ = (SRC) + \
        (size_t)(wave * 16 + (lane >> 2)) * (STRIDE) + \
        ((lane & 3) ^ ((lane >> 3) & 3)) * 8; \
    __builtin_amdgcn_global_load_lds( \
        (const __attribute__((address_space(1))) void*)g_, \
        (__attribute__((address_space(3))) void*)&DST[wave * 16][0], \
        16, 0, 0); \
  }

#define LOAD_A(AH) \
  f16x8 ah[4]; \
  _Pragma("unroll") \
  for (int m_ = 0; m_ < 4; ++m_) \
    ah[m_] = *(const f16x8*)&AH[wr * 64 + m_ * 16 + l15][(lg ^ sseg) * 8];

#define LOAD_B(BH) \
  f16x8 bh[4]; \
  _Pragma("unroll") \
  for (int n_ = 0; n_ < 4; ++n_) \
    bh[n_] = *(const f16x8*)&BH[wc * 64 + n_ * 16 + l15][(lg ^ sseg) * 8];

#define MFMA_TILE(ACC) \
  _Pragma("unroll") \
  for (int m_ = 0; m_ < 4; ++m_) \
    _Pragma("unroll") \
    for (int n_ = 0; n_ < 4; ++n_) \
      MFMA_F16(ACC[m_][n_], ah[m_], bh[n_]);

// ---------------- fused msg GEMM + adjacency bmm, fully double-buffered (round-4 proven) ----------------
// grid 2048 (1D, XCD-swizzled): wg>>1 = batch, wg&1 = d-half (both halves share h reads -> same XCD)
__global__ __launch_bounds__(256) void k_msgadj(const unsigned short* __restrict__ h,    // [NR][256]
                                                const unsigned short* __restrict__ W,    // msg_W[step] fp16 [1024][256]
                                                const float* __restrict__ bias,          // msg_b[step] [1024]
                                                const unsigned short* __restrict__ adjh, // fp16 [b][e][128][128]
                                                unsigned short* __restrict__ m_out) {    // [NR][256]
  __shared__ __align__(16) char pool[16384 + 128 * 136 * 2];   // 16KB buf0 + 34.8KB (buf1|PT)
  typedef unsigned short row32[32];
  row32* As_[2] = { (row32*)pool,          (row32*)(pool + 16384) };
  row32* Bs_[2] = { (row32*)(pool + 8192), (row32*)(pool + 24576) };
  unsigned short (*PT)[136] = (unsigned short (*)[136])(pool + 16384);
  GEMM_IDS
  XCD_SWZ(wg, 2048)
  const size_t b = wg >> 1;
  const int d0 = (wg & 1) * 128;
  const unsigned short* hb = h + (size_t)b * 128 * 256;
  const unsigned short* adjb = adjh + (size_t)b * 4 * 128 * 128;
  f32x4 accM[4][4] = {};
  for (int e = 0; e < 4; ++e) {
    f32x4 accP[4][4] = {};
    const unsigned short* We = W + (size_t)(e * 256 + d0) * 256;
    const unsigned short* adje = adjb + (size_t)e * 128 * 128;
    // ---- GEMM-1: 8 K-phases, 2-buffer depth-1 pipeline ----
    GLDS(hb, 256, As_[0])
    GLDS(We, 256, Bs_[0])
    #pragma unroll
    for (int k0i = 0; k0i < 8; ++k0i) {
      const int cur = k0i & 1;
      if (k0i < 7) {
        row32* an_ = As_[cur ^ 1];
        row32* bn_ = Bs_[cur ^ 1];
        GLDS(hb + (k0i + 1) * 32, 256, an_)
        GLDS(We + (k0i + 1) * 32, 256, bn_)
      } else {
        // last phase reads buf1; As0/Bs0 are free -> pre-stage adj(0), adj(1)
        GLDS(adje + 0 * 32, 128, As_[0])
        GLDS(adje + 1 * 32, 128, Bs_[0])
      }
      VWAIT(4);   // drain stage(k0i), keep the 4 just-issued
      BARR;
      {
        row32* ac_ = As_[cur];
        row32* bc_ = Bs_[cur];
        LOAD_A(ac_)
        LOAD_B(bc_)
        MFMA_TILE(accP)
      }
      BARR;
    }
    // ---- PT epilogue (writes alias buf1; GEMM-1 phase-7 reads are barrier-complete) ----
    #pragma unroll
    for (int m_ = 0; m_ < 4; ++m_) {
      int j0 = wr * 64 + m_ * 16 + lg * 4;
      #pragma unroll
      for (int n_ = 0; n_ < 4; ++n_) {
        int c = wc * 64 + n_ * 16 + l15;          // d-local
        float bb = bias[e * 256 + d0 + c];
        u16x4 o;
        #pragma unroll
        for (int q = 0; q < 4; ++q) o[q] = f2h(accP[m_][n_][q] + bb);
        *(u16x4*)&PT[c][j0] = o;
      }
    }
    LWAIT;   // commit ds_writes (raw barrier does not drain lgkm)
    BARR;
    // ---- adj-bmm: 4 phases, adj tiles ping-pong As0/Bs0, depth-1 ----
    #pragma unroll
    for (int kt = 0; kt < 4; ++kt) {
      if (kt == 1) { GLDS(adje + 2 * 32, 128, As_[0]) }   // adj(2) over adj(0)'s slot
      if (kt == 2) { GLDS(adje + 3 * 32, 128, Bs_[0]) }   // adj(3) over adj(1)'s slot
      if (kt < 3) { VWAIT(2); } else { VWAIT(0); }
      BARR;
      {
        row32* ac_ = (kt & 1) ? Bs_[0] : As_[0];
        LOAD_A(ac_)
        f16x8 bh[4];
        #pragma unroll
        for (int n_ = 0; n_ < 4; ++n_)
          bh[n_] = *(const f16x8*)&PT[wc * 64 + n_ * 16 + l15][kt * 32 + lg * 8];
        MFMA_TILE(accM)
      }
      BARR;
    }
  }
  #pragma unroll
  for (int m_ = 0; m_ < 4; ++m_) {
    int i0 = wr * 64 + m_ * 16 + lg * 4;
    #pragma unroll
    for (int n_ = 0; n_ < 4; ++n_) {
      int c = d0 + wc * 64 + n_ * 16 + l15;
      #pragma unroll
      for (int q = 0; q < 4; ++q)
        m_out[((size_t)b * 128 + i0 + q) * 256 + c] = f2h(accM[m_][n_][q]);
    }
  }
}

// ---------------- fused gates + GRU: 64x64 tile, 2-stage 32KB (post-T1 depth-1) ----------------
// grid 8192 (1D, XCD-swizzled): wg>>3 = batch, quad = wg&7; r0=(quad>>2)*64, c0=(quad&3)*64.
// r4 tested 2-stage PRE-T1 (HBM 900cy) and lost to 3-stage; post-T1 loads are L2-resident
// (~200cy, msgadj proves depth-1 suffices). 32KB LDS -> 5 blocks/CU x 4 waves = 20 waves/CU
// (VGPR 72 -> 7/SIMD cap = 28) vs 3-stage's 12. More resident waves = more latency cover
// for a barrier-synced loop whose per-phase fixed cost dominates.
template <bool HAS_H>
__global__ __launch_bounds__(256) void k_grufuse(const unsigned short* __restrict__ m,
                                                 const unsigned short* __restrict__ h,
                                                 const unsigned short* __restrict__ wih,  // [768][256]
                                                 const unsigned short* __restrict__ whh,  // [768][256]
                                                 const float* __restrict__ b_ih,
                                                 const float* __restrict__ b_hh,
                                                 unsigned short* __restrict__ h_new) {
  __shared__ unsigned short As[2][64][32];
  __shared__ unsigned short Br[2][64][32], Bz[2][64][32], Bn[2][64][32];
  GEMM_IDS
  XCD_SWZ(wg, 8192)
  const size_t b = wg >> 3;
  const int quad = wg & 7;
  const int r0 = (quad >> 2) * 64;
  const int c0 = (quad & 3) * 64;
  const unsigned short* msrc = m + ((size_t)b * 128 + r0) * 256;
  const unsigned short* hsrc = h + ((size_t)b * 128 + r0) * 256;
  constexpr int NKT = HAS_H ? 16 : 8;

  f32x4 accR[2][2] = {}, accZ[2][2] = {}, accI[2][2] = {}, accN[2][2] = {};

  auto stage = [&](int t, int s) {
    const unsigned short* a_ = ((HAS_H && t >= 8) ? hsrc : msrc) + (t & 7) * 32;
    const unsigned short* w_ = (HAS_H && t >= 8) ? whh : wih;
    GLDS64(a_, 256, As[s])
    GLDS64(w_ + (size_t)(c0) * 256 + (t & 7) * 32, 256, Br[s])
    GLDS64(w_ + (size_t)(256 + c0) * 256 + (t & 7) * 32, 256, Bz[s])
    GLDS64(w_ + (size_t)(512 + c0) * 256 + (t & 7) * 32, 256, Bn[s])
  };

  stage(0, 0);
  #pragma unroll
  for (int kt = 0; kt < NKT; ++kt) {
    const int cur = kt & 1;
    if (kt + 1 < NKT) stage(kt + 1, cur ^ 1);
    if (kt + 1 < NKT) { VWAIT(4); } else { VWAIT(0); }
    BARR;
    f16x8 af[2], brf[2], bzf[2], bnf[2];
    #pragma unroll
    for (int m_ = 0; m_ < 2; ++m_)
      af[m_] = *(const f16x8*)&As[cur][wr * 32 + m_ * 16 + l15][(lg ^ sseg) * 8];
    #pragma unroll
    for (int n_ = 0; n_ < 2; ++n_) {
      brf[n_] = *(const f16x8*)&Br[cur][wc * 32 + n_ * 16 + l15][(lg ^ sseg) * 8];
      bzf[n_] = *(const f16x8*)&Bz[cur][wc * 32 + n_ * 16 + l15][(lg ^ sseg) * 8];
      bnf[n_] = *(const f16x8*)&Bn[cur][wc * 32 + n_ * 16 + l15][(lg ^ sseg) * 8];
    }
    #pragma unroll
    for (int m_ = 0; m_ < 2; ++m_)
      #pragma unroll
      for (int n_ = 0; n_ < 2; ++n_) {
        MFMA_F16(accR[m_][n_], af[m_], brf[n_]);
        MFMA_F16(accZ[m_][n_], af[m_], bzf[n_]);
        if (!HAS_H || kt < 8) { MFMA_F16(accI[m_][n_], af[m_], bnf[n_]); }
        else                  { MFMA_F16(accN[m_][n_], af[m_], bnf[n_]); }
      }
    BARR;
  }

  // epilogue: full-f32 GRU combine
  #pragma unroll
  for (int m_ = 0; m_ < 2; ++m_) {
    int rloc = r0 + wr * 32 + m_ * 16 + lg * 4;
    #pragma unroll
    for (int n_ = 0; n_ < 2; ++n_) {
      int c = c0 + wc * 32 + n_ * 16 + l15;
      float br = b_ih[c] + b_hh[c];
      float bz = b_ih[256 + c] + b_hh[256 + c];
      float bin = b_ih[512 + c], bhn = b_hh[512 + c];
      #pragma unroll
      for (int q = 0; q < 4; ++q) {
        size_t row = (size_t)b * 128 + rloc + q;
        float r = sigm(accR[m_][n_][q] + br);
        float z = sigm(accZ[m_][n_][q] + bz);
        float hn = (HAS_H ? accN[m_][n_][q] : 0.f) + bhn;
        float nn = tanh_(accI[m_][n_][q] + bin + r * hn);
        float hv = HAS_H ? h2f(h[row * 256 + c]) : 0.f;
        h_new[row * 256 + c] = f2h((1.f - z) * nn + z * hv);
      }
    }
  }
}

// ---------------- fused readout (2-deep counted-vmcnt pipeline) ----------------
// grid 4096 (1D, XCD-swizzled): wg>>2 = batch, wg&3 = col-tile (4 sharers of h/h0)
__global__ __launch_bounds__(256) void k_readout(const unsigned short* __restrict__ h,
                                                 const unsigned short* __restrict__ h0,
                                                 const unsigned short* __restrict__ iw,   // [512][512]
                                                 const unsigned short* __restrict__ jw,   // [512][256]
                                                 const float* __restrict__ ib,
                                                 const float* __restrict__ jb,
                                                 float* __restrict__ out) {
  __shared__ unsigned short As[2][128][32];
  __shared__ unsigned short Bg[2][128][32], Bv[2][128][32];
  __shared__ float red[2][128];
  GEMM_IDS
  XCD_SWZ(wg, 4096)
  const size_t b = wg >> 2;
  const int c0 = (wg & 3) * 128;
  auto as_src = [&](int t) {
    return (t < 8) ? (h + b * 128 * 256 + t * 32) : (h0 + b * 128 * 256 + (t - 8) * 32);
  };
  f32x4 accG[4][4] = {};
  f32x4 accV[4][4] = {};
  GLDS(as_src(0), 256, As[0])
  GLDS(iw + (size_t)c0 * 512, 512, Bg[0])
  GLDS(jw + (size_t)c0 * 256, 256, Bv[0])
  #pragma unroll
  for (int kt = 0; kt < 16; ++kt) {
    const int cur = kt & 1;
    if (kt + 1 < 16) {
      GLDS(as_src(kt + 1), 256, As[cur ^ 1])
      GLDS(iw + (size_t)c0 * 512 + (kt + 1) * 32, 512, Bg[cur ^ 1])
      if (kt + 1 < 8) GLDS(jw + (size_t)c0 * 256 + (kt + 1) * 32, 256, Bv[cur ^ 1])
    }
    if (kt < 7) { VWAIT(6); } else if (kt < 15) { VWAIT(4); } else { VWAIT(0); }
    BARR;
    LOAD_A(As[cur])
    f16x8 bg[4];
    #pragma unroll
    for (int n_ = 0; n_ < 4; ++n_)
      bg[n_] = *(const f16x8*)&Bg[cur][wc * 64 + n_ * 16 + l15][(lg ^ sseg) * 8];
    #pragma unroll
    for (int m_ = 0; m_ < 4; ++m_)
      #pragma unroll
      for (int n_ = 0; n_ < 4; ++n_)
        MFMA_F16(accG[m_][n_], ah[m_], bg[n_]);
    if (kt < 8) {
      f16x8 bv[4];
      #pragma unroll
      for (int n_ = 0; n_ < 4; ++n_)
        bv[n_] = *(const f16x8*)&Bv[cur][wc * 64 + n_ * 16 + l15][(lg ^ sseg) * 8];
      #pragma unroll
      for (int m_ = 0; m_ < 4; ++m_)
        #pragma unroll
        for (int n_ = 0; n_ < 4; ++n_)
          MFMA_F16(accV[m_][n_], ah[m_], bv[n_]);
    }
    BARR;
  }
  #pragma unroll
  for (int n_ = 0; n_ < 4; ++n_) {
    int c = c0 + wc * 64 + n_ * 16 + l15;
    float gb = ib[c], vb = jb[c];
    float s = 0.f;
    #pragma unroll
    for (int m_ = 0; m_ < 4; ++m_)
      #pragma unroll
      for (int q = 0; q < 4; ++q) {
        float g = sigm(accG[m_][n_][q] + gb);
        float v = accV[m_][n_][q] + vb;
        s += g * v;
      }
    s += __shfl_xor(s, 16);
    s += __shfl_xor(s, 32);
    if (lg == 0) red[wr][wc * 64 + n_ * 16 + l15] = s;
  }
  __syncthreads();
  if (tid < 128) out[b * MOUT + c0 + tid] = red[0][tid] + red[1][tid];
}

// ---------------- host ----------------
extern "C" void kernel_launch(void* const* d_in, const int* in_sizes, int n_in,
                              void* d_out, int out_size, void* d_ws, size_t ws_size,
                              hipStream_t stream) {
  const int*   atom  = (const int*)d_in[0];
  const float* adj   = (const float*)d_in[1];
  const float* embed = (const float*)d_in[2];
  const float* msg_W = (const float*)d_in[3];
  const float* msg_b = (const float*)d_in[4];
  const float* W_ih  = (const float*)d_in[5];
  const float* b_ih  = (const float*)d_in[6];
  const float* W_hh  = (const float*)d_in[7];
  const float* b_hh  = (const float*)d_in[8];
  const float* i_W   = (const float*)d_in[9];
  const float* i_b   = (const float*)d_in[10];
  const float* j_W   = (const float*)d_in[11];
  const float* j_b   = (const float*)d_in[12];
  float* out = (float*)d_out;

  const size_t SZ_H   = (size_t)NR * 256 * 2;              // 67 MB
  const size_t SZ_ADJ = (size_t)NB * 4 * 128 * 128 * 2;    // 134 MB

  char* p = (char*)d_ws;
  unsigned short* hA   = (unsigned short*)p;  p += SZ_H;
  unsigned short* hB   = (unsigned short*)p;  p += SZ_H;
  unsigned short* h0   = (unsigned short*)p;  p += SZ_H;
  unsigned short* m    = (unsigned short*)p;  p += SZ_H;
  unsigned short* adjh = (unsigned short*)p;  p += SZ_ADJ;
  unsigned short* wmsg = (unsigned short*)p;  p += (size_t)3 * 1024 * 256 * 2;
  unsigned short* wih  = (unsigned short*)p;  p += (size_t)768 * 256 * 2;
  unsigned short* whh  = (unsigned short*)p;  p += (size_t)768 * 256 * 2;
  unsigned short* wiw  = (unsigned short*)p;  p += (size_t)512 * 512 * 2;
  unsigned short* wjw  = (unsigned short*)p;  p += (size_t)512 * 256 * 2;
  if ((size_t)(p - (char*)d_ws) > ws_size) return;  // insufficient workspace -> visible failure

  // converts: adj (BW-bound) + all 5 weights in one dispatch
  k_cvt<<<(int)((size_t)NB * 4 * 128 * 128 / 2048), 256, 0, stream>>>(adj, adjh);
  k_cvt5<<<768, 256, 0, stream>>>(msg_W, wmsg, W_ih, wih, W_hh, whh, i_W, wiw, j_W, wjw);

  // gather
  k_gather<<<(int)(NR * 64 / 256), 256, 0, stream>>>(atom, embed, hA, h0);

  unsigned short* h_cur = hA;
  unsigned short* h_nxt = hB;
  for (int step = 0; step < 3; ++step) {
    // fused: m = einsum(adj, reshape(h @ msg_W^T + msg_b))
    k_msgadj<<<2048, 256, 0, stream>>>(h_cur, wmsg + (size_t)step * 262144,
                                       msg_b + (size_t)step * 1024, adjh, m);
    if (step == 0)
      k_grufuse<false><<<8192, 256, 0, stream>>>(m, h_cur, wih, whh, b_ih, b_hh, h_nxt);
    else
      k_grufuse<true><<<8192, 256, 0, stream>>>(m, h_cur, wih, whh, b_ih, b_hh, h_nxt);
    unsigned short* t = h_cur; h_cur = h_nxt; h_nxt = t;
  }

  // fused gated readout
  k_readout<<<4096, 256, 0, stream>>>(h_cur, h0, wiw, wjw, i_b, j_b, out);
}

// Round 11
// 1100.649 us; speedup vs baseline: 1.6762x; 1.0296x over previous
//
#include <hip/hip_runtime.h>
#include <cstdint>
#include <cstddef>

using f32x4 = float __attribute__((ext_vector_type(4)));
using u16x8 = unsigned short __attribute__((ext_vector_type(8)));
using u16x4 = unsigned short __attribute__((ext_vector_type(4)));
typedef _Float16 f16x8 __attribute__((ext_vector_type(8)));

#define DEV static __device__ __forceinline__

DEV unsigned short f2h(float f) {            // f32 -> fp16 bits (RNE via v_cvt_f16_f32)
  _Float16 x = (_Float16)f;
  return __builtin_bit_cast(unsigned short, x);
}
DEV float h2f(unsigned short s) {
  return (float)__builtin_bit_cast(_Float16, s);
}
DEV float sigm(float x) { return 1.f / (1.f + __expf(-x)); }
DEV float tanh_(float x) { return 2.f / (1.f + __expf(-2.f * x)) - 1.f; }

#define MFMA_F16(acc, va, vb) \
  acc = __builtin_amdgcn_mfma_f32_16x16x32_f16(va, vb, acc, 0, 0, 0)

constexpr int NB = 1024;   // minibatch
constexpr int AT = 128;    // atoms
constexpr int DD = 256;    // hidden dim
constexpr int MOUT = 512;  // readout M
constexpr long NR = (long)NB * AT;   // 131072 rows

// counted-vmcnt wait + scheduling fences (rule #18: fence after asm wait)
#define VWAIT(n) do { asm volatile("s_waitcnt vmcnt(" #n ")" ::: "memory"); \
                      __builtin_amdgcn_sched_barrier(0); } while (0)
#define LWAIT do { asm volatile("s_waitcnt lgkmcnt(0)" ::: "memory"); \
                   __builtin_amdgcn_sched_barrier(0); } while (0)
#define BARR do { __builtin_amdgcn_sched_barrier(0); __builtin_amdgcn_s_barrier(); \
                  __builtin_amdgcn_sched_barrier(0); } while (0)

// XCD-chunked bijective swizzle (T1, proven round 5: FETCH 277->69 MB):
// blocks sharing operand panels become contiguous within one XCD's chunk.
// Requires n % 8 == 0 (all our grids are).
#define XCD_SWZ(WG, N) const int WG = ((int)blockIdx.x & 7) * ((N) / 8) + ((int)blockIdx.x >> 3);

// ---------------- generic f32 -> fp16 convert (8 elems/thread; n % 2048 == 0) ----------------
__global__ __launch_bounds__(256) void k_cvt(const float* __restrict__ src,
                                             unsigned short* __restrict__ dst) {
  long base = ((long)blockIdx.x * 256 + threadIdx.x) * 8;
  f32x4 v0 = *(const f32x4*)(src + base);
  f32x4 v1 = *(const f32x4*)(src + base + 4);
  u16x8 o;
  #pragma unroll
  for (int q = 0; q < 4; ++q) o[q] = f2h(v0[q]);
  #pragma unroll
  for (int q = 0; q < 4; ++q) o[4 + q] = f2h(v1[q]);
  *(u16x8*)(dst + base) = o;
}

// ---------------- merged weight converts: 5 tensors, one dispatch (768 blocks) ----------------
// blocks: [0,384) msg_W | [384,480) W_ih | [480,576) W_hh | [576,704) i_W | [704,768) j_W
__global__ __launch_bounds__(256) void k_cvt5(const float* __restrict__ s0, unsigned short* __restrict__ d0,
                                              const float* __restrict__ s1, unsigned short* __restrict__ d1,
                                              const float* __restrict__ s2, unsigned short* __restrict__ d2,
                                              const float* __restrict__ s3, unsigned short* __restrict__ d3,
                                              const float* __restrict__ s4, unsigned short* __restrict__ d4) {
  int blk = blockIdx.x;
  const float* s; unsigned short* d;
  if (blk < 384)      { s = s0; d = d0; }
  else if (blk < 480) { s = s1; d = d1; blk -= 384; }
  else if (blk < 576) { s = s2; d = d2; blk -= 480; }
  else if (blk < 704) { s = s3; d = d3; blk -= 576; }
  else                { s = s4; d = d4; blk -= 704; }
  long base = ((long)blk * 256 + threadIdx.x) * 8;
  f32x4 v0 = *(const f32x4*)(s + base);
  f32x4 v1 = *(const f32x4*)(s + base + 4);
  u16x8 o;
  #pragma unroll
  for (int q = 0; q < 4; ++q) o[q] = f2h(v0[q]);
  #pragma unroll
  for (int q = 0; q < 4; ++q) o[4 + q] = f2h(v1[q]);
  *(u16x8*)(d + base) = o;
}

// ---------------- embed gather: h and h0 (fp16) ----------------
__global__ __launch_bounds__(256) void k_gather(const int* __restrict__ atom,
                                                const float* __restrict__ embed,
                                                unsigned short* __restrict__ h,
                                                unsigned short* __restrict__ h0) {
  long idx = (long)blockIdx.x * 256 + threadIdx.x;   // NR*64 threads, 4 elems each
  long n = idx >> 6;
  int ch = (int)(idx & 63);
  int a = atom[n];
  f32x4 v = *(const f32x4*)(embed + (size_t)a * DD + ch * 4);
  u16x4 o;
  #pragma unroll
  for (int q = 0; q < 4; ++q) o[q] = f2h(v[q]);
  *(u16x4*)(h  + n * DD + ch * 4) = o;
  *(u16x4*)(h0 + n * DD + ch * 4) = o;
}

// ---- shared helpers ----
// LDS XOR-swizzle (proven round 3: conflicts 1.7e7 -> 0):
// store data-seg s of row r at physical seg p = s ^ ((r>>1)&3).
//   write side (DMA is linear): pre-swizzle GLOBAL source chunk per lane.
//   read side: physical seg = lg ^ ((l15>>1)&3).
#define GEMM_IDS \
  const int tid = threadIdx.x, lane = tid & 63, wave = tid >> 6; \
  const int wr = wave >> 1, wc = wave & 1; \
  const int l15 = lane & 15, lg = lane >> 4; \
  const int sseg = (l15 >> 1) & 3;

// async global -> LDS stage of a 128x32 fp16 tile (2 vmem ops/wave), source pre-swizzled
#define GLDS(SRC, STRIDE, DST) \
  { \
    _Pragma("unroll") \
    for (int j_ = 0; j_ < 2; ++j_) { \
      const unsigned short* g_ = (SRC) + \
          (size_t)((wave * 2 + j_) * 16 + (lane >> 2)) * (STRIDE) + \
          ((lane & 3) ^ ((lane >> 3) & 3)) * 8; \
      __builtin_amdgcn_global_load_lds( \
          (const __attribute__((address_space(1))) void*)g_, \
          (__attribute__((address_space(3))) void*)&DST[(wave * 2 + j_) * 16][0], \
          16, 0, 0); \
    } \
  }

// async global -> LDS stage of a 64x32 fp16 tile (1 vmem op/wave), source pre-swizzled
#define GLDS64(SRC, STRIDE, DST) \
  { \
    const unsigned short* g_ = (SRC) + \
        (size_t)(wave * 16 + (lane >> 2)) * (STRIDE) + \
        ((lane & 3) ^ ((lane >> 3) & 3)) * 8; \
    __builtin_amdgcn_global_load_lds( \
        (const __attribute__((address_space(1))) void*)g_, \
        (__attribute__((address_space(3))) void*)&DST[wave * 16][0], \
        16, 0, 0); \
  }

#define LOAD_A(AH) \
  f16x8 ah[4]; \
  _Pragma("unroll") \
  for (int m_ = 0; m_ < 4; ++m_) \
    ah[m_] = *(const f16x8*)&AH[wr * 64 + m_ * 16 + l15][(lg ^ sseg) * 8];

#define LOAD_B(BH) \
  f16x8 bh[4]; \
  _Pragma("unroll") \
  for (int n_ = 0; n_ < 4; ++n_) \
    bh[n_] = *(const f16x8*)&BH[wc * 64 + n_ * 16 + l15][(lg ^ sseg) * 8];

#define MFMA_TILE(ACC) \
  _Pragma("unroll") \
  for (int m_ = 0; m_ < 4; ++m_) \
    _Pragma("unroll") \
    for (int n_ = 0; n_ < 4; ++n_) \
      MFMA_F16(ACC[m_][n_], ah[m_], bh[n_]);

// ---------------- fused msg GEMM + adjacency bmm, fully double-buffered (round-4 proven) ----------------
// grid 2048 (1D, XCD-swizzled): wg>>1 = batch, wg&1 = d-half (both halves share h reads -> same XCD)
__global__ __launch_bounds__(256) void k_msgadj(const unsigned short* __restrict__ h,    // [NR][256]
                                                const unsigned short* __restrict__ W,    // msg_W[step] fp16 [1024][256]
                                                const float* __restrict__ bias,          // msg_b[step] [1024]
                                                const unsigned short* __restrict__ adjh, // fp16 [b][e][128][128]
                                                unsigned short* __restrict__ m_out) {    // [NR][256]
  __shared__ __align__(16) char pool[16384 + 128 * 136 * 2];   // 16KB buf0 + 34.8KB (buf1|PT)
  typedef unsigned short row32[32];
  row32* As_[2] = { (row32*)pool,          (row32*)(pool + 16384) };
  row32* Bs_[2] = { (row32*)(pool + 8192), (row32*)(pool + 24576) };
  unsigned short (*PT)[136] = (unsigned short (*)[136])(pool + 16384);
  GEMM_IDS
  XCD_SWZ(wg, 2048)
  const size_t b = wg >> 1;
  const int d0 = (wg & 1) * 128;
  const unsigned short* hb = h + (size_t)b * 128 * 256;
  const unsigned short* adjb = adjh + (size_t)b * 4 * 128 * 128;
  f32x4 accM[4][4] = {};
  for (int e = 0; e < 4; ++e) {
    f32x4 accP[4][4] = {};
    const unsigned short* We = W + (size_t)(e * 256 + d0) * 256;
    const unsigned short* adje = adjb + (size_t)e * 128 * 128;
    // ---- GEMM-1: 8 K-phases, 2-buffer depth-1 pipeline ----
    GLDS(hb, 256, As_[0])
    GLDS(We, 256, Bs_[0])
    #pragma unroll
    for (int k0i = 0; k0i < 8; ++k0i) {
      const int cur = k0i & 1;
      if (k0i < 7) {
        row32* an_ = As_[cur ^ 1];
        row32* bn_ = Bs_[cur ^ 1];
        GLDS(hb + (k0i + 1) * 32, 256, an_)
        GLDS(We + (k0i + 1) * 32, 256, bn_)
      } else {
        // last phase reads buf1; As0/Bs0 are free -> pre-stage adj(0), adj(1)
        GLDS(adje + 0 * 32, 128, As_[0])
        GLDS(adje + 1 * 32, 128, Bs_[0])
      }
      VWAIT(4);   // drain stage(k0i), keep the 4 just-issued
      BARR;
      {
        row32* ac_ = As_[cur];
        row32* bc_ = Bs_[cur];
        LOAD_A(ac_)
        LOAD_B(bc_)
        __builtin_amdgcn_s_setprio(1);
        MFMA_TILE(accP)
        __builtin_amdgcn_s_setprio(0);
      }
      BARR;
    }
    // ---- PT epilogue (writes alias buf1; GEMM-1 phase-7 reads are barrier-complete) ----
    #pragma unroll
    for (int m_ = 0; m_ < 4; ++m_) {
      int j0 = wr * 64 + m_ * 16 + lg * 4;
      #pragma unroll
      for (int n_ = 0; n_ < 4; ++n_) {
        int c = wc * 64 + n_ * 16 + l15;          // d-local
        float bb = bias[e * 256 + d0 + c];
        u16x4 o;
        #pragma unroll
        for (int q = 0; q < 4; ++q) o[q] = f2h(accP[m_][n_][q] + bb);
        *(u16x4*)&PT[c][j0] = o;
      }
    }
    LWAIT;   // commit ds_writes (raw barrier does not drain lgkm)
    BARR;
    // ---- adj-bmm: 4 phases, adj tiles ping-pong As0/Bs0, depth-1 ----
    #pragma unroll
    for (int kt = 0; kt < 4; ++kt) {
      if (kt == 1) { GLDS(adje + 2 * 32, 128, As_[0]) }   // adj(2) over adj(0)'s slot
      if (kt == 2) { GLDS(adje + 3 * 32, 128, Bs_[0]) }   // adj(3) over adj(1)'s slot
      if (kt < 3) { VWAIT(2); } else { VWAIT(0); }
      BARR;
      {
        row32* ac_ = (kt & 1) ? Bs_[0] : As_[0];
        LOAD_A(ac_)
        f16x8 bh[4];
        #pragma unroll
        for (int n_ = 0; n_ < 4; ++n_)
          bh[n_] = *(const f16x8*)&PT[wc * 64 + n_ * 16 + l15][kt * 32 + lg * 8];
        __builtin_amdgcn_s_setprio(1);
        MFMA_TILE(accM)
        __builtin_amdgcn_s_setprio(0);
      }
      BARR;
    }
  }
  #pragma unroll
  for (int m_ = 0; m_ < 4; ++m_) {
    int i0 = wr * 64 + m_ * 16 + lg * 4;
    #pragma unroll
    for (int n_ = 0; n_ < 4; ++n_) {
      int c = d0 + wc * 64 + n_ * 16 + l15;
      #pragma unroll
      for (int q = 0; q < 4; ++q)
        m_out[((size_t)b * 128 + i0 + q) * 256 + c] = f2h(accM[m_][n_][q]);
    }
  }
}

// ---------------- fused gates + GRU: 64x64 tile, 3-stage depth-2 pipeline (round-5 proven best) ----------------
// grid 8192 (1D, XCD-swizzled): wg>>3 = batch, quad = wg&7; r0=(quad>>2)*64, c0=(quad&3)*64.
// Structural matrix fully explored (r1-r10): {64x64/128x64 x 1/2/3-stage x 256/512-thread
// x no-LDS} -> this config is the measured minimum (196us). + T5 setprio around MFMA:
// 3 async blocks/CU at different phases = the regime where setprio pays (m191).
template <bool HAS_H>
__global__ __launch_bounds__(256) void k_grufuse(const unsigned short* __restrict__ m,
                                                 const unsigned short* __restrict__ h,
                                                 const unsigned short* __restrict__ wih,  // [768][256]
                                                 const unsigned short* __restrict__ whh,  // [768][256]
                                                 const float* __restrict__ b_ih,
                                                 const float* __restrict__ b_hh,
                                                 unsigned short* __restrict__ h_new) {
  __shared__ unsigned short As[3][64][32];
  __shared__ unsigned short Br[3][64][32], Bz[3][64][32], Bn[3][64][32];
  GEMM_IDS
  XCD_SWZ(wg, 8192)
  const size_t b = wg >> 3;
  const int quad = wg & 7;
  const int r0 = (quad >> 2) * 64;
  const int c0 = (quad & 3) * 64;
  const unsigned short* msrc = m + ((size_t)b * 128 + r0) * 256;
  const unsigned short* hsrc = h + ((size_t)b * 128 + r0) * 256;
  constexpr int NKT = HAS_H ? 16 : 8;

  f32x4 accR[2][2] = {}, accZ[2][2] = {}, accI[2][2] = {}, accN[2][2] = {};

  auto stage = [&](int t, int s) {
    const unsigned short* a_ = ((HAS_H && t >= 8) ? hsrc : msrc) + (t & 7) * 32;
    const unsigned short* w_ = (HAS_H && t >= 8) ? whh : wih;
    GLDS64(a_, 256, As[s])
    GLDS64(w_ + (size_t)(c0) * 256 + (t & 7) * 32, 256, Br[s])
    GLDS64(w_ + (size_t)(256 + c0) * 256 + (t & 7) * 32, 256, Bz[s])
    GLDS64(w_ + (size_t)(512 + c0) * 256 + (t & 7) * 32, 256, Bn[s])
  };

  stage(0, 0);
  stage(1, 1);
  #pragma unroll
  for (int kt = 0; kt < NKT; ++kt) {
    const int cur = kt % 3;
    if (kt + 2 < NKT) stage(kt + 2, (kt + 2) % 3);
    if (kt + 2 < NKT) { VWAIT(8); } else if (kt + 2 == NKT) { VWAIT(4); } else { VWAIT(0); }
    BARR;
    f16x8 af[2], brf[2], bzf[2], bnf[2];
    #pragma unroll
    for (int m_ = 0; m_ < 2; ++m_)
      af[m_] = *(const f16x8*)&As[cur][wr * 32 + m_ * 16 + l15][(lg ^ sseg) * 8];
    #pragma unroll
    for (int n_ = 0; n_ < 2; ++n_) {
      brf[n_] = *(const f16x8*)&Br[cur][wc * 32 + n_ * 16 + l15][(lg ^ sseg) * 8];
      bzf[n_] = *(const f16x8*)&Bz[cur][wc * 32 + n_ * 16 + l15][(lg ^ sseg) * 8];
      bnf[n_] = *(const f16x8*)&Bn[cur][wc * 32 + n_ * 16 + l15][(lg ^ sseg) * 8];
    }
    __builtin_amdgcn_s_setprio(1);
    #pragma unroll
    for (int m_ = 0; m_ < 2; ++m_)
      #pragma unroll
      for (int n_ = 0; n_ < 2; ++n_) {
        MFMA_F16(accR[m_][n_], af[m_], brf[n_]);
        MFMA_F16(accZ[m_][n_], af[m_], bzf[n_]);
        if (!HAS_H || kt < 8) { MFMA_F16(accI[m_][n_], af[m_], bnf[n_]); }
        else                  { MFMA_F16(accN[m_][n_], af[m_], bnf[n_]); }
      }
    __builtin_amdgcn_s_setprio(0);
    BARR;
  }

  // epilogue: full-f32 GRU combine
  #pragma unroll
  for (int m_ = 0; m_ < 2; ++m_) {
    int rloc = r0 + wr * 32 + m_ * 16 + lg * 4;
    #pragma unroll
    for (int n_ = 0; n_ < 2; ++n_) {
      int c = c0 + wc * 32 + n_ * 16 + l15;
      float br = b_ih[c] + b_hh[c];
      float bz = b_ih[256 + c] + b_hh[256 + c];
      float bin = b_ih[512 + c], bhn = b_hh[512 + c];
      #pragma unroll
      for (int q = 0; q < 4; ++q) {
        size_t row = (size_t)b * 128 + rloc + q;
        float r = sigm(accR[m_][n_][q] + br);
        float z = sigm(accZ[m_][n_][q] + bz);
        float hn = (HAS_H ? accN[m_][n_][q] : 0.f) + bhn;
        float nn = tanh_(accI[m_][n_][q] + bin + r * hn);
        float hv = HAS_H ? h2f(h[row * 256 + c]) : 0.f;
        h_new[row * 256 + c] = f2h((1.f - z) * nn + z * hv);
      }
    }
  }
}

// ---------------- fused readout (2-deep counted-vmcnt pipeline) ----------------
// grid 4096 (1D, XCD-swizzled): wg>>2 = batch, wg&3 = col-tile (4 sharers of h/h0)
__global__ __launch_bounds__(256) void k_readout(const unsigned short* __restrict__ h,
                                                 const unsigned short* __restrict__ h0,
                                                 const unsigned short* __restrict__ iw,   // [512][512]
                                                 const unsigned short* __restrict__ jw,   // [512][256]
                                                 const float* __restrict__ ib,
                                                 const float* __restrict__ jb,
                                                 float* __restrict__ out) {
  __shared__ unsigned short As[2][128][32];
  __shared__ unsigned short Bg[2][128][32], Bv[2][128][32];
  __shared__ float red[2][128];
  GEMM_IDS
  XCD_SWZ(wg, 4096)
  const size_t b = wg >> 2;
  const int c0 = (wg & 3) * 128;
  auto as_src = [&](int t) {
    return (t < 8) ? (h + b * 128 * 256 + t * 32) : (h0 + b * 128 * 256 + (t - 8) * 32);
  };
  f32x4 accG[4][4] = {};
  f32x4 accV[4][4] = {};
  GLDS(as_src(0), 256, As[0])
  GLDS(iw + (size_t)c0 * 512, 512, Bg[0])
  GLDS(jw + (size_t)c0 * 256, 256, Bv[0])
  #pragma unroll
  for (int kt = 0; kt < 16; ++kt) {
    const int cur = kt & 1;
    if (kt + 1 < 16) {
      GLDS(as_src(kt + 1), 256, As[cur ^ 1])
      GLDS(iw + (size_t)c0 * 512 + (kt + 1) * 32, 512, Bg[cur ^ 1])
      if (kt + 1 < 8) GLDS(jw + (size_t)c0 * 256 + (kt + 1) * 32, 256, Bv[cur ^ 1])
    }
    if (kt < 7) { VWAIT(6); } else if (kt < 15) { VWAIT(4); } else { VWAIT(0); }
    BARR;
    LOAD_A(As[cur])
    f16x8 bg[4];
    #pragma unroll
    for (int n_ = 0; n_ < 4; ++n_)
      bg[n_] = *(const f16x8*)&Bg[cur][wc * 64 + n_ * 16 + l15][(lg ^ sseg) * 8];
    __builtin_amdgcn_s_setprio(1);
    #pragma unroll
    for (int m_ = 0; m_ < 4; ++m_)
      #pragma unroll
      for (int n_ = 0; n_ < 4; ++n_)
        MFMA_F16(accG[m_][n_], ah[m_], bg[n_]);
    __builtin_amdgcn_s_setprio(0);
    if (kt < 8) {
      f16x8 bv[4];
      #pragma unroll
      for (int n_ = 0; n_ < 4; ++n_)
        bv[n_] = *(const f16x8*)&Bv[cur][wc * 64 + n_ * 16 + l15][(lg ^ sseg) * 8];
      __builtin_amdgcn_s_setprio(1);
      #pragma unroll
      for (int m_ = 0; m_ < 4; ++m_)
        #pragma unroll
        for (int n_ = 0; n_ < 4; ++n_)
          MFMA_F16(accV[m_][n_], ah[m_], bv[n_]);
      __builtin_amdgcn_s_setprio(0);
    }
    BARR;
  }
  #pragma unroll
  for (int n_ = 0; n_ < 4; ++n_) {
    int c = c0 + wc * 64 + n_ * 16 + l15;
    float gb = ib[c], vb = jb[c];
    float s = 0.f;
    #pragma unroll
    for (int m_ = 0; m_ < 4; ++m_)
      #pragma unroll
      for (int q = 0; q < 4; ++q) {
        float g = sigm(accG[m_][n_][q] + gb);
        float v = accV[m_][n_][q] + vb;
        s += g * v;
      }
    s += __shfl_xor(s, 16);
    s += __shfl_xor(s, 32);
    if (lg == 0) red[wr][wc * 64 + n_ * 16 + l15] = s;
  }
  __syncthreads();
  if (tid < 128) out[b * MOUT + c0 + tid] = red[0][tid] + red[1][tid];
}

// ---------------- host ----------------
extern "C" void kernel_launch(void* const* d_in, const int* in_sizes, int n_in,
                              void* d_out, int out_size, void* d_ws, size_t ws_size,
                              hipStream_t stream) {
  const int*   atom  = (const int*)d_in[0];
  const float* adj   = (const float*)d_in[1];
  const float* embed = (const float*)d_in[2];
  const float* msg_W = (const float*)d_in[3];
  const float* msg_b = (const float*)d_in[4];
  const float* W_ih  = (const float*)d_in[5];
  const float* b_ih  = (const float*)d_in[6];
  const float* W_hh  = (const float*)d_in[7];
  const float* b_hh  = (const float*)d_in[8];
  const float* i_W   = (const float*)d_in[9];
  const float* i_b   = (const float*)d_in[10];
  const float* j_W   = (const float*)d_in[11];
  const float* j_b   = (const float*)d_in[12];
  float* out = (float*)d_out;

  const size_t SZ_H   = (size_t)NR * 256 * 2;              // 67 MB
  const size_t SZ_ADJ = (size_t)NB * 4 * 128 * 128 * 2;    // 134 MB

  char* p = (char*)d_ws;
  unsigned short* hA   = (unsigned short*)p;  p += SZ_H;
  unsigned short* hB   = (unsigned short*)p;  p += SZ_H;
  unsigned short* h0   = (unsigned short*)p;  p += SZ_H;
  unsigned short* m    = (unsigned short*)p;  p += SZ_H;
  unsigned short* adjh = (unsigned short*)p;  p += SZ_ADJ;
  unsigned short* wmsg = (unsigned short*)p;  p += (size_t)3 * 1024 * 256 * 2;
  unsigned short* wih  = (unsigned short*)p;  p += (size_t)768 * 256 * 2;
  unsigned short* whh  = (unsigned short*)p;  p += (size_t)768 * 256 * 2;
  unsigned short* wiw  = (unsigned short*)p;  p += (size_t)512 * 512 * 2;
  unsigned short* wjw  = (unsigned short*)p;  p += (size_t)512 * 256 * 2;
  if ((size_t)(p - (char*)d_ws) > ws_size) return;  // insufficient workspace -> visible failure

  // converts: adj (BW-bound) + all 5 weights in one dispatch
  k_cvt<<<(int)((size_t)NB * 4 * 128 * 128 / 2048), 256, 0, stream>>>(adj, adjh);
  k_cvt5<<<768, 256, 0, stream>>>(msg_W, wmsg, W_ih, wih, W_hh, whh, i_W, wiw, j_W, wjw);

  // gather
  k_gather<<<(int)(NR * 64 / 256), 256, 0, stream>>>(atom, embed, hA, h0);

  unsigned short* h_cur = hA;
  unsigned short* h_nxt = hB;
  for (int step = 0; step < 3; ++step) {
    // fused: m = einsum(adj, reshape(h @ msg_W^T + msg_b))
    k_msgadj<<<2048, 256, 0, stream>>>(h_cur, wmsg + (size_t)step * 262144,
                                       msg_b + (size_t)step * 1024, adjh, m);
    if (step == 0)
      k_grufuse<false><<<8192, 256, 0, stream>>>(m, h_cur, wih, whh, b_ih, b_hh, h_nxt);
    else
      k_grufuse<true><<<8192, 256, 0, stream>>>(m, h_cur, wih, whh, b_ih, b_hh, h_nxt);
    unsigned short* t = h_cur; h_cur = h_nxt; h_nxt = t;
  }

  // fused gated readout
  k_readout<<<4096, 256, 0, stream>>>(h_cur, h0, wiw, wjw, i_b, j_b, out);
}